// Round 1
// baseline (957.996 us; speedup 1.0000x reference)
//
#include <hip/hip_runtime.h>

#define H 512
#define W 512
#define TILE 48
#define HALO 12
#define STAGE (TILE + 2 * HALO)      // 72
#define SPX (STAGE * STAGE)          // 5184
#define NT 256
#define KCHUNKS ((SPX + NT - 1) / NT)  // 21
#define TPX (TILE * TILE)            // 2304
#define TCHUNKS (TPX / NT)           // 9
#define TPD ((H + TILE - 1) / TILE)  // 11
#define NUM_ITER 10
#define NBANKS 16
#define BANK_STRIDE 16               // doubles; 128B apart to avoid line contention

__device__ __forceinline__ float sigmf(float x) {
  return 1.0f / (1.0f + __expf(-x));
}

// soft_erode = min(3x1 minpool, 1x3 minpool) = min over cross neighborhood.
__device__ __forceinline__ void erode_sweep(const float* __restrict__ src,
                                            float* __restrict__ dst,
                                            const unsigned int* packs, int tid) {
#pragma unroll
  for (int k = 0; k < KCHUNKS; ++k) {
    int i = tid + k * NT;
    if (i >= SPX) continue;
    unsigned int m = (packs[k >> 3] >> ((k & 7) * 4)) & 15u;
    int up = i - ((m & 1u) ? STAGE : 0);
    int dn = i + ((m & 2u) ? STAGE : 0);
    int lf = i - ((m & 4u) ? 1 : 0);
    int rt = i + ((m & 8u) ? 1 : 0);
    float v = src[i];
    float vm = fminf(fminf(src[up], src[dn]), v);
    float hm = fminf(fminf(src[lf], src[rt]), v);
    dst[i] = fminf(vm, hm);
  }
}

// soft_dilate = 3x3 maxpool (clamped indices == SAME with -inf pad).
__device__ __forceinline__ void dilate_sweep(const float* __restrict__ src,
                                             float* __restrict__ dst,
                                             const unsigned int* packs, int tid) {
#pragma unroll
  for (int k = 0; k < KCHUNKS; ++k) {
    int i = tid + k * NT;
    if (i >= SPX) continue;
    unsigned int m = (packs[k >> 3] >> ((k & 7) * 4)) & 15u;
    int up = i - ((m & 1u) ? STAGE : 0);
    int dn = i + ((m & 2u) ? STAGE : 0);
    int dl = (m & 4u) ? 1 : 0;
    int dr = (m & 8u) ? 1 : 0;
    float a = fmaxf(fmaxf(src[up - dl], src[up + dr]), src[up]);
    float b = fmaxf(fmaxf(src[i - dl], src[i + dr]), src[i]);
    float c = fmaxf(fmaxf(src[dn - dl], src[dn + dr]), src[dn]);
    dst[i] = fmaxf(fmaxf(a, b), c);
  }
}

__global__ __launch_bounds__(NT) void cl_skel_kernel(
    const float* __restrict__ pred, const float* __restrict__ target,
    double* __restrict__ sums) {
  __shared__ float bufA[SPX];
  __shared__ float bufB[SPX];
  __shared__ float bufC[SPX];
  __shared__ float rbuf[2][NT / 64];

  const int tid = threadIdx.x;
  const int tileIdx = blockIdx.x;
  const int batch = blockIdx.y;
  const bool isPred = (blockIdx.z == 0);
  const int tr = (tileIdx / TPD) * TILE;
  const int tc = (tileIdx % TPD) * TILE;
  const int gr0 = tr - HALO;
  const int gc0 = tc - HALO;
  const float* __restrict__ img = isPred ? pred : target;
  const float* __restrict__ other = isPred ? target : pred;
  const size_t base = (size_t)batch * (H * W);

  // Per-pixel neighbor-validity nibbles (clamp at stage border for the
  // harmless contaminated ring; clamp at TRUE image border == SAME padding).
  unsigned int packs[(KCHUNKS + 7) / 8];
#pragma unroll
  for (int p = 0; p < (KCHUNKS + 7) / 8; ++p) packs[p] = 0u;
#pragma unroll
  for (int k = 0; k < KCHUNKS; ++k) {
    int i = tid + k * NT;
    if (i >= SPX) continue;
    int r = i / STAGE;
    int c = i - r * STAGE;
    int gr = gr0 + r;
    int gc = gc0 + c;
    unsigned int m = 0u;
    if (r > 0 && gr > 0) m |= 1u;
    if (r < STAGE - 1 && gr < H - 1) m |= 2u;
    if (c > 0 && gc > 0) m |= 4u;
    if (c < STAGE - 1 && gc < W - 1) m |= 8u;
    packs[k >> 3] |= (m << ((k & 7) * 4));
  }

  // Stage load with replicated (clamped) global coords; sigmoid for pred.
#pragma unroll
  for (int k = 0; k < KCHUNKS; ++k) {
    int i = tid + k * NT;
    if (i >= SPX) continue;
    int r = i / STAGE;
    int c = i - r * STAGE;
    int gr = min(max(gr0 + r, 0), H - 1);
    int gc = min(max(gc0 + c, 0), W - 1);
    float v = img[base + (size_t)gr * W + gc];
    if (isPred) v = sigmf(v);
    bufA[i] = v;
  }

  // Stage indices of this thread's tile pixels.
  int sidx[TCHUNKS];
#pragma unroll
  for (int k = 0; k < TCHUNKS; ++k) {
    int j = tid + k * NT;
    int r = j / TILE;
    int c = j - r * TILE;
    sidx[k] = (r + HALO) * STAGE + (c + HALO);
  }

  __syncthreads();

  // skel = relu(img - dilate(erode(img)))
  erode_sweep(bufA, bufB, packs, tid);
  __syncthreads();
  dilate_sweep(bufB, bufC, packs, tid);
  __syncthreads();

  float skel[TCHUNKS];
#pragma unroll
  for (int k = 0; k < TCHUNKS; ++k) {
    float d = bufA[sidx[k]] - bufC[sidx[k]];
    skel[k] = d > 0.0f ? d : 0.0f;
  }
  // No sync needed here: the next write (Y=bufB) is not read by the code above.

  float* X = bufA;  // holds x_{i-1}
  float* Y = bufB;
  float* Z = bufC;
#pragma unroll 1
  for (int it = 0; it < NUM_ITER; ++it) {
    erode_sweep(X, Y, packs, tid);  // Y = x_i = erode(x_{i-1})
    __syncthreads();
    erode_sweep(Y, Z, packs, tid);  // Z = erode(x_i)
    __syncthreads();
    dilate_sweep(Z, X, packs, tid);  // X = open(x_i)  (x_{i-1} dead)
    __syncthreads();
#pragma unroll
    for (int k = 0; k < TCHUNKS; ++k) {
      float d = Y[sidx[k]] - X[sidx[k]];
      d = d > 0.0f ? d : 0.0f;
      float u = d - skel[k] * d;
      skel[k] += (u > 0.0f ? u : 0.0f);
    }
    // rotate so X holds x_i; next iteration's first write (old Z) is unread,
    // and its second write happens after a barrier, so no sync needed here.
    float* t = X;
    X = Y;
    Y = Z;
    Z = t;
  }

  // Products with the other image over valid tile pixels, then reduce.
  float s0 = 0.0f, s1 = 0.0f;
#pragma unroll
  for (int k = 0; k < TCHUNKS; ++k) {
    int j = tid + k * NT;
    int r = j / TILE;
    int c = j - r * TILE;
    int gr = tr + r;
    int gc = tc + c;
    if (gr < H && gc < W) {
      float o = other[base + (size_t)gr * W + gc];
      if (!isPred) o = sigmf(o);  // other image is pred -> needs sigmoid
      s0 += skel[k];
      s1 += skel[k] * o;
    }
  }
#pragma unroll
  for (int off = 32; off > 0; off >>= 1) {
    s0 += __shfl_down(s0, off, 64);
    s1 += __shfl_down(s1, off, 64);
  }
  const int wave = tid >> 6;
  const int lane = tid & 63;
  if (lane == 0) {
    rbuf[0][wave] = s0;
    rbuf[1][wave] = s1;
  }
  __syncthreads();
  if (tid == 0) {
    float t0 = 0.0f, t1 = 0.0f;
#pragma unroll
    for (int w = 0; w < NT / 64; ++w) {
      t0 += rbuf[0][w];
      t1 += rbuf[1][w];
    }
    const int bank = (int)(blockIdx.x & (NBANKS - 1));
    const int o = (isPred ? 0 : 2);
    atomicAdd(&sums[bank * BANK_STRIDE + o], (double)t0);
    atomicAdd(&sums[bank * BANK_STRIDE + o + 1], (double)t1);
  }
}

__global__ void cl_finalize_kernel(const double* __restrict__ sums,
                                   float* __restrict__ out) {
  double s[4] = {0.0, 0.0, 0.0, 0.0};
  for (int b = 0; b < NBANKS; ++b)
    for (int j = 0; j < 4; ++j) s[j] += sums[b * BANK_STRIDE + j];
  double tprec = (s[1] + 1.0) / (s[0] + 1.0);
  double tsens = (s[3] + 1.0) / (s[2] + 1.0);
  double cl = 2.0 * tprec * tsens / (tprec + tsens + 1e-7);
  out[0] = (float)(1.0 - cl);
}

extern "C" void kernel_launch(void* const* d_in, const int* in_sizes, int n_in,
                              void* d_out, int out_size, void* d_ws,
                              size_t ws_size, hipStream_t stream) {
  const float* pred = (const float*)d_in[0];
  const float* target = (const float*)d_in[1];
  double* sums = (double*)d_ws;
  const int batch = in_sizes[0] / (H * W);  // 32

  hipMemsetAsync(d_ws, 0, NBANKS * BANK_STRIDE * sizeof(double), stream);
  dim3 grid(TPD * TPD, batch, 2);
  cl_skel_kernel<<<grid, NT, 0, stream>>>(pred, target, sums);
  cl_finalize_kernel<<<1, 1, 0, stream>>>(sums, (float*)d_out);
}

// Round 2
// 678.587 us; speedup vs baseline: 1.4118x; 1.4118x over previous
//
#include <hip/hip_runtime.h>

#define H 512
#define W 512
#define TILE 32
#define NT 256
#define BW 64                 // LDS row stride (floats), 16B-aligned rows
#define BROWS 58
#define BUFSZ (BROWS * BW)    // 3712 floats = 14848 B per buffer
#define TPD (W / TILE)        // 16 tiles per dim
#define NBANKS 16
#define BANK_STRIDE 16
// Geometry: image-tile pixel (y,x) lives at LDS (13+y, 16+x).
// Guard ring (clamp semantics at true image borders): rows 12/45, cols 15/48.

__device__ __forceinline__ float sigmf(float x) {
  return 1.0f / (1.0f + __expf(-x));
}
__device__ __forceinline__ float min3(float a, float b, float c) {
  return fminf(fminf(a, b), c);
}
__device__ __forceinline__ float max3(float a, float b, float c) {
  return fmaxf(fmaxf(a, b), c);
}
__device__ __forceinline__ float4 ld4(const float* p) {
  return *(const float4*)p;
}
__device__ __forceinline__ void st4(float* p, float4 v) {
  *(float4*)p = v;
}

// Erode (cross min) over centered region of radius R around the tile.
// Output cols [16-R, 47+R] (4-aligned padded), rows [13-R, 44+R].
template <int R>
__device__ __forceinline__ void erode(const float* __restrict__ src,
                                      float* __restrict__ dst, int tid) {
  constexpr int rb0 = 13 - R;
  constexpr int gc0 = (16 - R) & ~3;
  constexpr int G = ((47 + R - gc0) >> 2) + 1;
  constexpr int ROWS = 32 + 2 * R;
  constexpr int ITEMS = ROWS * G;
#pragma unroll
  for (int it = tid; it < ITEMS; it += NT) {
    int row = it / G;                       // constant divisor -> magic mul
    int g = it - row * G;
    int addr = (rb0 + row) * BW + gc0 + 4 * g;
    float4 v = ld4(src + addr);
    float4 u = ld4(src + addr - BW);
    float4 d = ld4(src + addr + BW);
    float l = src[addr - 1], r = src[addr + 4];
    float4 o;
    o.x = fminf(min3(u.x, d.x, v.x), fminf(l, v.y));
    o.y = fminf(min3(u.y, d.y, v.y), fminf(v.x, v.z));
    o.z = fminf(min3(u.z, d.z, v.z), fminf(v.y, v.w));
    o.w = fminf(min3(u.w, d.w, v.w), fminf(v.z, r));
    st4(dst + addr, o);
  }
}

// Refresh the clamp-guard ring of buffer f after an erode of radius R.
// Only called for blocks whose tile touches a true image border.
__device__ void refresh(float* __restrict__ f, int R, bool top, bool bot,
                        bool lft, bool rgt, int tid) {
  int side = tid >> 6;
  int p = tid & 63;
  int clo = 16 - R, chi = 47 + R;
  int rlo = 13 - R, rhi = 44 + R;
  if (side == 0 && top) {
    int c = clo + p;
    if (c <= chi) {
      int sc = c;
      if (lft) sc = max(sc, 16);
      if (rgt) sc = min(sc, 47);
      f[12 * BW + c] = f[13 * BW + sc];
    }
  } else if (side == 1 && bot) {
    int c = clo + p;
    if (c <= chi) {
      int sc = c;
      if (lft) sc = max(sc, 16);
      if (rgt) sc = min(sc, 47);
      f[45 * BW + c] = f[44 * BW + sc];
    }
  } else if (side == 2 && lft) {
    int r_ = rlo + p;
    if (r_ <= rhi) {
      int sr = r_;
      if (top) sr = max(sr, 13);
      if (bot) sr = min(sr, 44);
      f[r_ * BW + 15] = f[sr * BW + 16];
    }
  } else if (side == 3 && rgt) {
    int r_ = rlo + p;
    if (r_ <= rhi) {
      int sr = r_;
      if (top) sr = max(sr, 13);
      if (bot) sr = min(sr, 44);
      f[r_ * BW + 48] = f[sr * BW + 47];
    }
  }
}

// 3x3 max (dilate) of f at the thread's 4 tile px -> registers; skel update.
__device__ __forceinline__ void dilate_update(const float* __restrict__ f,
                                              int ca, float4 t0,
                                              float4& skel) {
  float4 a = ld4(f + ca - BW);
  float4 b = ld4(f + ca);
  float4 c = ld4(f + ca + BW);
  float la = f[ca - BW - 1], ra = f[ca - BW + 4];
  float lb = f[ca - 1], rb = f[ca + 4];
  float lc = f[ca + BW - 1], rc = f[ca + BW + 4];
  float4 m;
  m.x = max3(max3(la, a.x, a.y), max3(lb, b.x, b.y), max3(lc, c.x, c.y));
  m.y = max3(max3(a.x, a.y, a.z), max3(b.x, b.y, b.z), max3(c.x, c.y, c.z));
  m.z = max3(max3(a.y, a.z, a.w), max3(b.y, b.z, b.w), max3(c.y, c.z, c.w));
  m.w = max3(max3(a.z, a.w, ra), max3(b.z, b.w, rb), max3(c.z, c.w, rc));
  float d0 = fmaxf(t0.x - m.x, 0.0f);
  float d1 = fmaxf(t0.y - m.y, 0.0f);
  float d2 = fmaxf(t0.z - m.z, 0.0f);
  float d3 = fmaxf(t0.w - m.w, 0.0f);
  skel.x += fmaxf(fmaf(-skel.x, d0, d0), 0.0f);
  skel.y += fmaxf(fmaf(-skel.y, d1, d1), 0.0f);
  skel.z += fmaxf(fmaf(-skel.z, d2, d2), 0.0f);
  skel.w += fmaxf(fmaf(-skel.w, d3, d3), 0.0f);
}

__global__ __launch_bounds__(NT, 4) void cl_skel_kernel(
    const float* __restrict__ pred, const float* __restrict__ target,
    double* __restrict__ sums) {
  __shared__ float buf[2][BUFSZ];
  __shared__ float rbuf[2][NT / 64];

  const int tid = threadIdx.x;
  const int tileIdx = blockIdx.x;
  const int batch = blockIdx.y;
  const bool isPred = (blockIdx.z == 0);
  const int tr = (tileIdx / TPD) * TILE;
  const int tc = (tileIdx % TPD) * TILE;
  const float* __restrict__ img = isPred ? pred : target;
  const float* __restrict__ other = isPred ? target : pred;
  const size_t base = (size_t)batch * (H * W);

  const bool top = (tr == 0), lft = (tc == 0);
  const bool bot = (tr == H - TILE), rgt = (tc == W - TILE);
  const bool border = top | lft | bot | rgt;

  // ---- Stage x0: LDS rows 0..57, cols 0..59 (15 float4 groups) ----
  if (!border) {
#pragma unroll
    for (int it = tid; it < BROWS * 15; it += NT) {
      int row = it / 15;
      int g = it - row * 15;
      int gr = tr - 13 + row;
      int gc = tc - 16 + 4 * g;
      float4 v = ld4(&img[base + (size_t)gr * W + gc]);
      if (isPred) {
        v.x = sigmf(v.x); v.y = sigmf(v.y); v.z = sigmf(v.z); v.w = sigmf(v.w);
      }
      st4(&buf[0][row * BW + 4 * g], v);
    }
  } else {
#pragma unroll 2
    for (int it = tid; it < BROWS * 15; it += NT) {
      int row = it / 15;
      int g = it - row * 15;
      int gr = min(max(tr - 13 + row, 0), H - 1);
      int gc = tc - 16 + 4 * g;
      float4 v;
      v.x = img[base + (size_t)gr * W + min(max(gc + 0, 0), W - 1)];
      v.y = img[base + (size_t)gr * W + min(max(gc + 1, 0), W - 1)];
      v.z = img[base + (size_t)gr * W + min(max(gc + 2, 0), W - 1)];
      v.w = img[base + (size_t)gr * W + min(max(gc + 3, 0), W - 1)];
      if (isPred) {
        v.x = sigmf(v.x); v.y = sigmf(v.y); v.z = sigmf(v.z); v.w = sigmf(v.w);
      }
      st4(&buf[0][row * BW + 4 * g], v);
    }
  }
  __syncthreads();

  const int ty = tid >> 3;          // 0..31 tile row
  const int tg = tid & 7;           // 0..7  tile col group
  const int ca = (13 + ty) * BW + 16 + 4 * tg;

  float4 skel = make_float4(0.0f, 0.0f, 0.0f, 0.0f);

#define ITER(R, SRC, DST)                                   \
  {                                                         \
    float4 t0 = ld4(&SRC[ca]);                              \
    erode<R>(SRC, DST, tid);                                \
    __syncthreads();                                        \
    if (border) {                                           \
      refresh(DST, R, top, bot, lft, rgt, tid);             \
      __syncthreads();                                      \
    }                                                       \
    dilate_update(DST, ca, t0, skel);                       \
  }

  ITER(11, buf[0], buf[1])
  ITER(10, buf[1], buf[0])
  ITER(9, buf[0], buf[1])
  ITER(8, buf[1], buf[0])
  ITER(7, buf[0], buf[1])
  ITER(6, buf[1], buf[0])
  ITER(5, buf[0], buf[1])
  ITER(4, buf[1], buf[0])
  ITER(3, buf[0], buf[1])
  ITER(2, buf[1], buf[0])
  ITER(1, buf[0], buf[1])
#undef ITER

  // ---- Products with the other image over this thread's 4 tile px ----
  float4 o = ld4(&other[base + (size_t)(tr + ty) * W + tc + 4 * tg]);
  if (!isPred) {
    o.x = sigmf(o.x); o.y = sigmf(o.y); o.z = sigmf(o.z); o.w = sigmf(o.w);
  }
  float s0 = (skel.x + skel.y) + (skel.z + skel.w);
  float s1 = (skel.x * o.x + skel.y * o.y) + (skel.z * o.z + skel.w * o.w);

#pragma unroll
  for (int off = 32; off > 0; off >>= 1) {
    s0 += __shfl_down(s0, off, 64);
    s1 += __shfl_down(s1, off, 64);
  }
  const int wave = tid >> 6;
  const int lane = tid & 63;
  if (lane == 0) {
    rbuf[0][wave] = s0;
    rbuf[1][wave] = s1;
  }
  __syncthreads();
  if (tid == 0) {
    float t0 = 0.0f, t1 = 0.0f;
#pragma unroll
    for (int w = 0; w < NT / 64; ++w) {
      t0 += rbuf[0][w];
      t1 += rbuf[1][w];
    }
    const int bank = (int)(blockIdx.x & (NBANKS - 1));
    const int o2 = (isPred ? 0 : 2);
    atomicAdd(&sums[bank * BANK_STRIDE + o2], (double)t0);
    atomicAdd(&sums[bank * BANK_STRIDE + o2 + 1], (double)t1);
  }
}

__global__ void cl_finalize_kernel(const double* __restrict__ sums,
                                   float* __restrict__ out) {
  double s[4] = {0.0, 0.0, 0.0, 0.0};
  for (int b = 0; b < NBANKS; ++b)
    for (int j = 0; j < 4; ++j) s[j] += sums[b * BANK_STRIDE + j];
  double tprec = (s[1] + 1.0) / (s[0] + 1.0);
  double tsens = (s[3] + 1.0) / (s[2] + 1.0);
  double cl = 2.0 * tprec * tsens / (tprec + tsens + 1e-7);
  out[0] = (float)(1.0 - cl);
}

extern "C" void kernel_launch(void* const* d_in, const int* in_sizes, int n_in,
                              void* d_out, int out_size, void* d_ws,
                              size_t ws_size, hipStream_t stream) {
  const float* pred = (const float*)d_in[0];
  const float* target = (const float*)d_in[1];
  double* sums = (double*)d_ws;
  const int batch = in_sizes[0] / (H * W);  // 32

  hipMemsetAsync(d_ws, 0, NBANKS * BANK_STRIDE * sizeof(double), stream);
  dim3 grid(TPD * TPD, batch, 2);
  cl_skel_kernel<<<grid, NT, 0, stream>>>(pred, target, sums);
  cl_finalize_kernel<<<1, 1, 0, stream>>>(sums, (float*)d_out);
}

// Round 3
// 346.428 us; speedup vs baseline: 2.7653x; 1.9588x over previous
//
#include <hip/hip_runtime.h>

#define H 512
#define W 512
#define TILE 32
#define NT 256
#define BW 64                 // LDS row stride (floats)
#define BROWS 58
#define BUFSZ (BROWS * BW)    // 3712 floats = 14848 B per buffer
#define TPD (W / TILE)        // 16 tiles per dim
#define NBANKS 16
#define BANK_STRIDE 16
// Tile pixel (y,x) lives at LDS (13+y, 16+x). Guard rows 12/45.
// Columns are full-width [0,64); strip-edge garbage stays >=4 cols outside
// the needed validity region (radius 12-k after k erodes).

__device__ __forceinline__ float sigmf(float x) {
  return 1.0f / (1.0f + __expf(-x));
}
__device__ __forceinline__ float min3f(float a, float b, float c) {
  return fminf(fminf(a, b), c);
}
__device__ __forceinline__ float max3f(float a, float b, float c) {
  return fmaxf(fmaxf(a, b), c);
}
__device__ __forceinline__ float4 ld4(const float* p) { return *(const float4*)p; }
__device__ __forceinline__ void st4(float* p, float4 v) { *(float4*)p = v; }

__global__ __launch_bounds__(NT) void cl_skel_kernel(
    const float* __restrict__ pred, const float* __restrict__ target,
    double* __restrict__ sums) {
  __shared__ float buf0[BUFSZ];
  __shared__ float buf1[BUFSZ];
  __shared__ float eL[40];      // compact copies of col 15 (rows 12..45)
  __shared__ float eR[40];      // col 48
  __shared__ float rbuf[2][NT / 64];

  const int tid = threadIdx.x;
  const int tileIdx = blockIdx.x;
  const int batch = blockIdx.y;
  const bool isPred = (blockIdx.z == 0);
  const int tr = (tileIdx / TPD) * TILE;
  const int tc = (tileIdx % TPD) * TILE;
  const float* __restrict__ img = isPred ? pred : target;
  const float* __restrict__ other = isPred ? target : pred;
  const size_t base = (size_t)batch * (H * W);

  const bool top = (tr == 0), lft = (tc == 0);
  const bool bot = (tr == H - TILE), rgt = (tc == W - TILE);
  const bool border = top | lft | bot | rgt;

  // ---- Stage x0: rows 0..57, full 16 float4 groups (cols 0..63) ----
  if (!border) {
    for (int it = tid; it < BROWS * 16; it += NT) {
      int row = it >> 4, g = it & 15;
      int gr = tr - 13 + row;
      int gc = tc - 16 + 4 * g;
      float4 v = ld4(&img[base + (size_t)gr * W + gc]);
      if (isPred) {
        v.x = sigmf(v.x); v.y = sigmf(v.y); v.z = sigmf(v.z); v.w = sigmf(v.w);
      }
      st4(&buf0[row * BW + 4 * g], v);
    }
  } else {
    for (int it = tid; it < BROWS * 16; it += NT) {
      int row = it >> 4, g = it & 15;
      int gr = min(max(tr - 13 + row, 0), H - 1);
      int gc = tc - 16 + 4 * g;
      float4 v;
      v.x = img[base + (size_t)gr * W + min(max(gc + 0, 0), W - 1)];
      v.y = img[base + (size_t)gr * W + min(max(gc + 1, 0), W - 1)];
      v.z = img[base + (size_t)gr * W + min(max(gc + 2, 0), W - 1)];
      v.w = img[base + (size_t)gr * W + min(max(gc + 3, 0), W - 1)];
      if (isPred) {
        v.x = sigmf(v.x); v.y = sigmf(v.y); v.z = sigmf(v.z); v.w = sigmf(v.w);
      }
      st4(&buf0[row * BW + 4 * g], v);
    }
  }
  __syncthreads();

  const int ty = tid >> 3;  // 0..31 tile row
  const int tg = tid & 7;   // 0..7  tile col group
  const int ca = (13 + ty) * BW + 16 + 4 * tg;

  float4 skel = make_float4(0.0f, 0.0f, 0.0f, 0.0f);
  float* src = buf0;
  float* dst = buf1;

#pragma unroll 1
  for (int R = 11; R >= 1; --R) {
    float4 t0 = ld4(src + ca);  // x_k at own pixels (pre-erode)

    // ---- erode src->dst over rows [13-R, 44+R], full width, row pairs ----
    {
      const int rb = 13 - R;
      const int items = (16 + R) << 4;  // (ROWS/2) * 16
      for (int it = tid; it < items; it += NT) {
        int rp = it >> 4, g = it & 15;
        int a = (rb + 2 * rp) * BW + 4 * g;
        float4 um = ld4(src + a - BW);
        float4 v0 = ld4(src + a);
        float4 v1 = ld4(src + a + BW);
        float4 dn = ld4(src + a + 2 * BW);
        float l0 = __shfl_up(v0.w, 1, 16);
        float r0 = __shfl_down(v0.x, 1, 16);
        float l1 = __shfl_up(v1.w, 1, 16);
        float r1 = __shfl_down(v1.x, 1, 16);
        float4 o0, o1;
        o0.x = fminf(min3f(um.x, v0.x, v1.x), fminf(l0, v0.y));
        o0.y = fminf(min3f(um.y, v0.y, v1.y), fminf(v0.x, v0.z));
        o0.z = fminf(min3f(um.z, v0.z, v1.z), fminf(v0.y, v0.w));
        o0.w = fminf(min3f(um.w, v0.w, v1.w), fminf(v0.z, r0));
        o1.x = fminf(min3f(v0.x, v1.x, dn.x), fminf(l1, v1.y));
        o1.y = fminf(min3f(v0.y, v1.y, dn.y), fminf(v1.x, v1.z));
        o1.z = fminf(min3f(v0.z, v1.z, dn.z), fminf(v1.y, v1.w));
        o1.w = fminf(min3f(v0.w, v1.w, dn.w), fminf(v1.z, r1));
        st4(dst + a, o0);
        st4(dst + a + BW, o1);
      }
    }
    __syncthreads();

    // ---- guard-row refresh (exact clamp for dilate) + edge-column copy ----
    if (top && tid >= 128 && tid < 192) {
      int c = tid - 128;
      int sc = min(max(c, lft ? 16 : 0), rgt ? 47 : 63);
      dst[12 * BW + c] = dst[13 * BW + sc];
    }
    if (bot && tid >= 192) {
      int c = tid - 192;
      int sc = min(max(c, lft ? 16 : 0), rgt ? 47 : 63);
      dst[45 * BW + c] = dst[44 * BW + sc];
    }
    if (tid < 34) {
      int sr = min(max(12 + tid, top ? 13 : 12), bot ? 44 : 45);
      eL[tid] = dst[sr * BW + (lft ? 16 : 15)];
    } else if (tid >= 64 && tid < 98) {
      int i = tid - 64;
      int sr = min(max(12 + i, top ? 13 : 12), bot ? 44 : 45);
      eR[i] = dst[sr * BW + (rgt ? 47 : 48)];
    }
    __syncthreads();

    // ---- dilate(dst) at own 4 px (reads only, no hazard with next erode) ----
    {
      float4 vm = ld4(dst + ca - BW);
      float4 v0 = ld4(dst + ca);
      float4 vp = ld4(dst + ca + BW);
      float lm = __shfl_up(vm.w, 1, 8), rm = __shfl_down(vm.x, 1, 8);
      float l0 = __shfl_up(v0.w, 1, 8), r0 = __shfl_down(v0.x, 1, 8);
      float lp = __shfl_up(vp.w, 1, 8), rp = __shfl_down(vp.x, 1, 8);
      if (tg == 0) { lm = eL[ty]; l0 = eL[ty + 1]; lp = eL[ty + 2]; }
      if (tg == 7) { rm = eR[ty]; r0 = eR[ty + 1]; rp = eR[ty + 2]; }
      float4 hm, h0, hp;
      hm.x = max3f(lm, vm.x, vm.y);
      hm.y = max3f(vm.x, vm.y, vm.z);
      hm.z = max3f(vm.y, vm.z, vm.w);
      hm.w = max3f(vm.z, vm.w, rm);
      h0.x = max3f(l0, v0.x, v0.y);
      h0.y = max3f(v0.x, v0.y, v0.z);
      h0.z = max3f(v0.y, v0.z, v0.w);
      h0.w = max3f(v0.z, v0.w, r0);
      hp.x = max3f(lp, vp.x, vp.y);
      hp.y = max3f(vp.x, vp.y, vp.z);
      hp.z = max3f(vp.y, vp.z, vp.w);
      hp.w = max3f(vp.z, vp.w, rp);
      float d0 = fmaxf(t0.x - max3f(hm.x, h0.x, hp.x), 0.0f);
      float d1 = fmaxf(t0.y - max3f(hm.y, h0.y, hp.y), 0.0f);
      float d2 = fmaxf(t0.z - max3f(hm.z, h0.z, hp.z), 0.0f);
      float d3 = fmaxf(t0.w - max3f(hm.w, h0.w, hp.w), 0.0f);
      skel.x += fmaxf(fmaf(-skel.x, d0, d0), 0.0f);
      skel.y += fmaxf(fmaf(-skel.y, d1, d1), 0.0f);
      skel.z += fmaxf(fmaf(-skel.z, d2, d2), 0.0f);
      skel.w += fmaxf(fmaf(-skel.w, d3, d3), 0.0f);
    }
    float* t = src; src = dst; dst = t;
  }

  // ---- Products with the other image over this thread's 4 tile px ----
  float4 o = ld4(&other[base + (size_t)(tr + ty) * W + tc + 4 * tg]);
  if (!isPred) {
    o.x = sigmf(o.x); o.y = sigmf(o.y); o.z = sigmf(o.z); o.w = sigmf(o.w);
  }
  float s0 = (skel.x + skel.y) + (skel.z + skel.w);
  float s1 = (skel.x * o.x + skel.y * o.y) + (skel.z * o.z + skel.w * o.w);

#pragma unroll
  for (int off = 32; off > 0; off >>= 1) {
    s0 += __shfl_down(s0, off, 64);
    s1 += __shfl_down(s1, off, 64);
  }
  const int wave = tid >> 6;
  const int lane = tid & 63;
  if (lane == 0) {
    rbuf[0][wave] = s0;
    rbuf[1][wave] = s1;
  }
  __syncthreads();
  if (tid == 0) {
    float t0 = 0.0f, t1 = 0.0f;
#pragma unroll
    for (int w = 0; w < NT / 64; ++w) {
      t0 += rbuf[0][w];
      t1 += rbuf[1][w];
    }
    const int bank = (int)(blockIdx.x & (NBANKS - 1));
    const int o2 = (isPred ? 0 : 2);
    atomicAdd(&sums[bank * BANK_STRIDE + o2], (double)t0);
    atomicAdd(&sums[bank * BANK_STRIDE + o2 + 1], (double)t1);
  }
}

__global__ void cl_finalize_kernel(const double* __restrict__ sums,
                                   float* __restrict__ out) {
  double s[4] = {0.0, 0.0, 0.0, 0.0};
  for (int b = 0; b < NBANKS; ++b)
    for (int j = 0; j < 4; ++j) s[j] += sums[b * BANK_STRIDE + j];
  double tprec = (s[1] + 1.0) / (s[0] + 1.0);
  double tsens = (s[3] + 1.0) / (s[2] + 1.0);
  double cl = 2.0 * tprec * tsens / (tprec + tsens + 1e-7);
  out[0] = (float)(1.0 - cl);
}

extern "C" void kernel_launch(void* const* d_in, const int* in_sizes, int n_in,
                              void* d_out, int out_size, void* d_ws,
                              size_t ws_size, hipStream_t stream) {
  const float* pred = (const float*)d_in[0];
  const float* target = (const float*)d_in[1];
  double* sums = (double*)d_ws;
  const int batch = in_sizes[0] / (H * W);  // 32

  hipMemsetAsync(d_ws, 0, NBANKS * BANK_STRIDE * sizeof(double), stream);
  dim3 grid(TPD * TPD, batch, 2);
  cl_skel_kernel<<<grid, NT, 0, stream>>>(pred, target, sums);
  cl_finalize_kernel<<<1, 1, 0, stream>>>(sums, (float*)d_out);
}